// Round 18
// baseline (49.957 us; speedup 1.0000x reference)
//
#include <hip/hip_runtime.h>

typedef _Float16 f16x8  __attribute__((ext_vector_type(8)));
typedef _Float16 f16x4  __attribute__((ext_vector_type(4)));
typedef __fp16   hf2    __attribute__((ext_vector_type(2)));
typedef float    f32x4  __attribute__((ext_vector_type(4)));

namespace {
constexpr int kN = 4, kL = 1024, kS = 1024, kH = 16, kE = 64, kD = 64;
constexpr int kRowF = kH * kE;     // 1024 floats: s-row stride of K and V
constexpr int KVB = 64;            // keys per LDS chunk
constexpr int NCH = kS / KVB;      // 16 chunks
constexpr float SCL = 0.125f * 1.44269504088896340736f;  // 1/sqrt(E)*log2(e)
}

__device__ __forceinline__ f16x4 pk4(float a, float b, float c, float d) {
  union { hf2 h2[2]; f16x4 v; } u;
  u.h2[0] = __builtin_amdgcn_cvt_pkrtz(a, b);
  u.h2[1] = __builtin_amdgcn_cvt_pkrtz(c, d);
  return u.v;
}
// cross-half-wave (lane ^32) max/sum via permlane32_swap (pure VALU)
__device__ __forceinline__ float xmax32(float t) {
  union { float f; unsigned u; } tu; tu.f = t;
  auto P = __builtin_amdgcn_permlane32_swap(tu.u, tu.u, false, false);
  union { unsigned u; float f; } a, b; a.u = P[0]; b.u = P[1];
  return fmaxf(a.f, b.f);
}
__device__ __forceinline__ float xsum32(float t) {
  union { float f; unsigned u; } tu; tu.f = t;
  auto P = __builtin_amdgcn_permlane32_swap(tu.u, tu.u, false, false);
  union { unsigned u; float f; } a, b; a.u = P[0]; b.u = P[1];
  return a.f + b.f;
}

// Detect all-zero mask/key_lengths: F[0] stays 0 iff every element is zero.
__global__ __launch_bounds__(256)
void flag_kernel(const float* __restrict__ M, const float* __restrict__ KLN,
                 unsigned* __restrict__ F)
{
  constexpr size_t nM = (size_t)kL * kS / 4, nK = (size_t)kN * kS / 4;
  unsigned any = 0;
  for (size_t i = (size_t)blockIdx.x * 256 + threadIdx.x; i < nM + nK;
       i += (size_t)gridDim.x * 256) {
    const f32x4 v = (i < nM) ? reinterpret_cast<const f32x4*>(M)[i]
                             : reinterpret_cast<const f32x4*>(KLN)[i - nM];
    #pragma unroll
    for (int r = 0; r < 4; ++r)
      any |= (__float_as_uint(v[r]) << 1);   // <<1 drops sign: -0 counts as 0
  }
  if (__any(any != 0) && (threadIdx.x & 63) == 0) atomicOr(F, 1u);
}

// 4-WAVES-PER-SIMD TLP: the 32q/wave geometry structurally caps the chip at
// 2048 waves (2/SIMD) and every intra-wave restructure (R10/R11/R17) was
// null -- the kernel is latency-bound. 16q/wave doubles wave count: block =
// 8 waves x 16 q = 128 q; grid 512 = 2 blocks/CU = 16 waves/CU. VGPR capped
// at 128 via launch_bounds(512,4) (per-wave state is light: acc = 4xf32x4).
// Fragment math is the rounds-1-5 VERIFIED 16x16 set: swapped scores S^T =
// K.Q^T via mfma_16x16x32_f16 (A-row = s = lane&15-indexed, B-col = q =
// lane&15; C/D col=lane&15=q, row=4*(lane>>4)+r=s); P^T feeds PV
// (O^T = V^T.P^T, mfma_16x16x16f16) DIRECTLY from registers (C/D row
// layout == K=16 B-frag layout -- no cross-lane pack needed). XOR slot
// swizzles (R5, measured 0 conflicts): K write b64 slot sc4^((s&7)<<1),
// K read b128 koff = qc*64 + ((g^(qc&7))<<3) (^32 for hf=1); V write slot
// srow^hw(d), V read slot (4st+g)^hv(t). R16 discipline: role-split reg
// staging (waves 0-3 K, 4-7 V), defer-max THR=8, named/const-idx state
// only (rule #20), one __syncthreads per chunk, 2-deep prefetch, mask-skip.
__global__ __launch_bounds__(512, 4)
void attn_fwd_kernel(const float* __restrict__ Q, const float* __restrict__ K,
                     const float* __restrict__ V, const float* __restrict__ M,
                     const float* __restrict__ KLN, float* __restrict__ O,
                     const unsigned* __restrict__ F)
{
  __shared__ _Float16 Ks[2][KVB * 64];   // 16 KB
  __shared__ _Float16 Vt[2][kD * 64];    // 16 KB

  const int tid  = threadIdx.x;
  const int lane = tid & 63;
  const int wave = tid >> 6;      // 0..7
  const int qc   = lane & 15;     // q col; also s-row (QK A) / d-row (PV A)
  const int g    = lane >> 4;     // 16-lane group 0..3
  const bool kRole = (wave < 4);  // staging role (wave-uniform)
  const int stid = tid & 255;     // staging id within role
  const int srow = stid >> 4;     // 0..15
  const int scol = stid & 15;     // float4 column

  const int useMask = F ? (int)F[0] : 1;   // uniform

  // XCD swizzle (512 % 8 == 0 -> bijective)
  const int swz = ((blockIdx.x & 7) << 6) | (blockIdx.x >> 3);
  const int nh = swz >> 3, qb = swz & 7;
  const int h = nh & (kH - 1), n = nh >> 4;
  const int qrow = qb * 128 + wave * 16 + qc;

  const float* Kp = K + ((size_t)n * kS * kH + h) * kE;
  const float* Vp = V + ((size_t)n * kS * kH + h) * kD;
  const float* Lp = KLN + (size_t)n * kS;
  const float* Mp = M + (size_t)qrow * kS;

  // ---- hoisted Q B-frags (pre-scaled): e = 32*hf + 8*g + j ----
  f16x8 qf0, qf1;
  {
    const float* Qp = Q + ((size_t)((size_t)n * kL + qrow) * kH + h) * kE;
    const f32x4 a0 = *reinterpret_cast<const f32x4*>(Qp + 8*g);
    const f32x4 b0 = *reinterpret_cast<const f32x4*>(Qp + 8*g + 4);
    const f32x4 a1 = *reinterpret_cast<const f32x4*>(Qp + 32 + 8*g);
    const f32x4 b1 = *reinterpret_cast<const f32x4*>(Qp + 32 + 8*g + 4);
    union { f16x4 h4[2]; f16x8 v; } u0, u1;
    u0.h4[0] = pk4(a0[0]*SCL, a0[1]*SCL, a0[2]*SCL, a0[3]*SCL);
    u0.h4[1] = pk4(b0[0]*SCL, b0[1]*SCL, b0[2]*SCL, b0[3]*SCL);
    u1.h4[0] = pk4(a1[0]*SCL, a1[1]*SCL, a1[2]*SCL, a1[3]*SCL);
    u1.h4[1] = pk4(b1[0]*SCL, b1[1]*SCL, b1[2]*SCL, b1[3]*SCL);
    qf0 = u0.v; qf1 = u1.v;
  }

  // ---- per-thread LDS constants (R5 verified 16x16 math) ----
  const int koff = qc*64 + ((g ^ (qc & 7)) << 3);   // + st*1024, ^32 for hf=1
  int hv[4], vrow[4];
  #pragma unroll
  for (int t = 0; t < 4; ++t) {
    hv[t] = (qc ^ (4*t + (qc >> 2))) & 15;
    vrow[t] = (16*t + qc) * 64;
  }
  int hwv[4];
  #pragma unroll
  for (int jd = 0; jd < 4; ++jd)
    hwv[jd] = ((4*(scol & 3) + jd) ^ scol) & 15;

  const f32x4 z4 = {0.f, 0.f, 0.f, 0.f};
  f32x4 acc[4] = {z4, z4, z4, z4};
  float mrun = -1e30f, lsum = 0.f;

  // ---- role-split staging: K waves load 4 K-rows, V waves one V quad ----
  f32x4 sg[4];
  auto load_kv = [&](int sbase) {
    if (kRole) {
      #pragma unroll
      for (int i = 0; i < 4; ++i)
        sg[i] = *reinterpret_cast<const f32x4*>(Kp + (size_t)(sbase + 16*i + srow) * kRowF + 4*scol);
    } else {
      #pragma unroll
      for (int js = 0; js < 4; ++js)
        sg[js] = *reinterpret_cast<const f32x4*>(Vp + (size_t)(sbase + 4*srow + js) * kRowF + 4*scol);
    }
  };
  auto kv_write = [&](int buf) {
    if (kRole) {
      #pragma unroll
      for (int i = 0; i < 4; ++i) {
        const int s = 16*i + srow;
        *reinterpret_cast<f16x4*>(&Ks[buf][s*64 + ((scol ^ ((s & 7) << 1)) << 2)]) =
            pk4(sg[i][0], sg[i][1], sg[i][2], sg[i][3]);
      }
    } else {
      #pragma unroll
      for (int jd = 0; jd < 4; ++jd) {
        const int d = 4*scol + jd;
        *reinterpret_cast<f16x4*>(&Vt[buf][d*64 + ((srow ^ hwv[jd]) << 2)]) =
            pk4(sg[0][jd], sg[1][jd], sg[2][jd], sg[3][jd]);
      }
    }
  };

  // ---- prologue: chunk 0 staged, chunk 1 in flight ----
  load_kv(0);
  kv_write(0);
  load_kv(KVB);

  for (int c = 0; c < NCH; ++c) {
    const int cur = c & 1;
    const int s0 = c * KVB;
    __syncthreads();
    if (c + 1 < NCH) kv_write(cur ^ 1);        // chunk c+1 (loaded body c-1)
    if (c + 2 < NCH) load_kv((c + 2) * KVB);   // written top of body c+1

    // ---- QK^T: 4 16-key s-tiles, E=64 in two K=32 halves ----
    f32x4 cc[4];
    __builtin_amdgcn_s_setprio(1);
    #pragma unroll
    for (int st = 0; st < 4; ++st) {
      const f16x8 kf0 = *reinterpret_cast<const f16x8*>(&Ks[cur][st*1024 + koff]);
      const f16x8 kf1 = *reinterpret_cast<const f16x8*>(&Ks[cur][st*1024 + (koff ^ 32)]);
      f32x4 t = z4;
      t = __builtin_amdgcn_mfma_f32_16x16x32_f16(kf0, qf0, t, 0, 0, 0);
      t = __builtin_amdgcn_mfma_f32_16x16x32_f16(kf1, qf1, t, 0, 0, 0);
      cc[st] = t;
    }
    __builtin_amdgcn_s_setprio(0);

    // ---- logits ----
    float x[16];
    if (useMask) {
      #pragma unroll
      for (int st = 0; st < 4; ++st) {
        const f32x4 mv = *reinterpret_cast<const f32x4*>(Mp + s0 + st*16 + 4*g);
        const f32x4 lv = *reinterpret_cast<const f32x4*>(Lp + s0 + st*16 + 4*g);
        #pragma unroll
        for (int r = 0; r < 4; ++r)
          x[st*4+r] = fmaf(mv[r] + lv[r], SCL, cc[st][r]);
      }
    } else {
      #pragma unroll
      for (int st = 0; st < 4; ++st)
        #pragma unroll
        for (int r = 0; r < 4; ++r)
          x[st*4+r] = cc[st][r];
    }

    // ---- online softmax: in-lane tree + shfl16 + permlane32 max ----
    float mx[8];
    #pragma unroll
    for (int i = 0; i < 8; ++i) mx[i] = fmaxf(x[i], x[i+8]);
    #pragma unroll
    for (int w = 4; w >= 1; w >>= 1)
      #pragma unroll
      for (int i = 0; i < w; ++i) mx[i] = fmaxf(mx[i], mx[i+w]);
    float tmax = fmaxf(mx[0], __shfl_xor(mx[0], 16));
    tmax = xmax32(tmax);

    if (!__all(tmax <= mrun + 8.f)) {          // defer-max THR=8 (log2)
      const float mnew = fmaxf(mrun, tmax);
      const float rs = __builtin_amdgcn_exp2f(mrun - mnew);
      mrun = mnew; lsum *= rs;
      acc[0] *= rs; acc[1] *= rs; acc[2] *= rs; acc[3] *= rs;
    }
    #pragma unroll
    for (int i = 0; i < 16; ++i)
      x[i] = __builtin_amdgcn_exp2f(x[i] - mrun);
    float s8[8];
    #pragma unroll
    for (int i = 0; i < 8; ++i) s8[i] = x[i] + x[i+8];
    #pragma unroll
    for (int w = 4; w >= 1; w >>= 1)
      #pragma unroll
      for (int i = 0; i < w; ++i) s8[i] += s8[i+w];
    lsum += s8[0];                              // cross-lane sum deferred

    // ---- P packs straight into PV B-frags (k = 4g+j == C/D row) ----
    f16x4 pb[4];
    #pragma unroll
    for (int st = 0; st < 4; ++st)
      pb[st] = pk4(x[st*4+0], x[st*4+1], x[st*4+2], x[st*4+3]);

    // ---- PV: 4 d-tiles x 4 s-tiles of 16x16x16 (conflict-free b64) ----
    __builtin_amdgcn_s_setprio(1);
    #pragma unroll
    for (int t = 0; t < 4; ++t) {
      #pragma unroll
      for (int st = 0; st < 4; ++st) {
        const int slot = ((4*st + g) ^ hv[t]) << 2;
        const f16x4 vf = *reinterpret_cast<const f16x4*>(&Vt[cur][vrow[t] + slot]);
        acc[t] = __builtin_amdgcn_mfma_f32_16x16x16f16(vf, pb[st], acc[t], 0, 0, 0);
      }
    }
    __builtin_amdgcn_s_setprio(0);
  }

  // ---- epilogue: finish lsum cross-lane, normalize, store ----
  lsum += __shfl_xor(lsum, 16);
  lsum = xsum32(lsum);
  const float inv = 1.f / lsum;
  float* Op = O + (((size_t)n * kL + qrow) * kH + h) * kD;
  #pragma unroll
  for (int t = 0; t < 4; ++t) {
    f32x4 o;
    o[0] = acc[t][0] * inv;
    o[1] = acc[t][1] * inv;
    o[2] = acc[t][2] * inv;
    o[3] = acc[t][3] * inv;
    *reinterpret_cast<f32x4*>(Op + 16*t + 4*g) = o;
  }
}

extern "C" void kernel_launch(void* const* d_in, const int* in_sizes, int n_in,
                              void* d_out, int out_size, void* d_ws, size_t ws_size,
                              hipStream_t stream) {
  const float* Q   = (const float*)d_in[0];
  const float* K   = (const float*)d_in[1];
  const float* V   = (const float*)d_in[2];
  const float* M   = (const float*)d_in[3];
  const float* KLN = (const float*)d_in[4];
  float* O = (float*)d_out;

  unsigned* F = nullptr;
  if (ws_size >= sizeof(unsigned)) {
    F = (unsigned*)d_ws;
    hipMemsetAsync(F, 0, sizeof(unsigned), stream);
    flag_kernel<<<dim3(1024), dim3(256), 0, stream>>>(M, KLN, F);
  }

  dim3 grid(kN * kH * (kL / 128));  // 512 blocks (128 q-rows each)
  dim3 block(512);                  // 8 waves, 16 queries each
  attn_fwd_kernel<<<grid, block, 0, stream>>>(Q, K, V, M, KLN, O, F);
}